// Round 3
// baseline (441.899 us; speedup 1.0000x reference)
//
#include <hip/hip_runtime.h>

#define B_   512
#define T_   365
#define DD_  5
#define DS_  27
#define H_   256
#define ROWS 2
#define NBLK (B_ / ROWS)      // 256 blocks = 1 per CU
#define NW   8
#define NTHR (NW * 64)        // 512 threads

typedef _Float16 half8_t __attribute__((ext_vector_type(8)));
typedef float    f32x4   __attribute__((ext_vector_type(4)));

#define LOG2E_ 1.4426950408889634f

__device__ __forceinline__ float sigmoid_f(float x) {
    return __builtin_amdgcn_rcpf(1.0f + __builtin_amdgcn_exp2f(-x * LOG2E_));
}
__device__ __forceinline__ float tanh_f(float x) {
    return 1.0f - 2.0f * __builtin_amdgcn_rcpf(1.0f + __builtin_amdgcn_exp2f(2.0f * LOG2E_ * x));
}

__global__ __launch_bounds__(NTHR, 2)
void ealstm_kernel(const float* __restrict__ xdyn,   // [B,T,DD]
                   const float* __restrict__ xstat,  // [B,DS]
                   const float* __restrict__ Wi, const float* __restrict__ bi,
                   const float* __restrict__ Wf, const float* __restrict__ bf_,
                   const float* __restrict__ Wg, const float* __restrict__ bg,
                   const float* __restrict__ Wo, const float* __restrict__ bo,
                   const float* __restrict__ Wh, const float* __restrict__ bh,
                   float* __restrict__ out)
{
    const int tid = threadIdx.x;
    const int l   = tid & 63;
    const int w   = tid >> 6;
    const int b0  = blockIdx.x * ROWS;

    // h double-buffer: 16 rows (MFMA M) x 264 f16 (528B pitch)
    __shared__ __align__(16) _Float16 hbuf[2][16][264];
    __shared__ float xsh[ROWS][T_ * DD_];
    __shared__ float red[NW];

    // zero both h buffers (rows >= ROWS stay zero forever)
    {
        _Float16* hz = &hbuf[0][0][0];
        for (int i = tid; i < 2 * 16 * 264; i += NTHR) hz[i] = (_Float16)0.0f;
    }
    // preload x_dynamic for this block's rows
    for (int i = tid; i < ROWS * T_ * DD_; i += NTHR) {
        int r   = i / (T_ * DD_);
        int rem = i - r * (T_ * DD_);
        xsh[r][rem] = xdyn[(size_t)(b0 + r) * (T_ * DD_) + rem];
    }

    // ---- persistent B fragments (h-part weights, fp16, MFMA 16x16x32 layout)
    // wave w owns cols [w*32, w*32+32) as two 16x16 tiles, both matrices.
    // lane l holds B[k = ks*32 + 8*(l>>4) + i][col = tile_col + (l&15)]
    const int colW = w * 32;
    const int lg   = l >> 4;
    const int lm   = l & 15;
    half8_t Bf[2][2][8];
    {
#pragma unroll
        for (int m = 0; m < 2; ++m) {
            const float* Ws = (m == 0) ? Wg : Wo;
#pragma unroll
            for (int tt = 0; tt < 2; ++tt) {
#pragma unroll
                for (int ks = 0; ks < 8; ++ks) {
                    int col = colW + tt * 16 + lm;
                    int k   = ks * 32 + 8 * lg;
                    const float* p = Ws + (size_t)(DD_ + k) * H_ + col;
                    half8_t v;
#pragma unroll
                    for (int i = 0; i < 8; ++i) v[i] = (_Float16)p[(size_t)i * H_];
                    Bf[m][tt][ks] = v;
                }
            }
        }
    }

    // ---- epilogue lane state: lanes 0..15 own 4 elems (rows 0,1 x cols c0,c1)
    const int c0 = colW + lm;
    const int c1 = c0 + 16;
    const bool epi = (l < 16);

    float iG[2][2], fG[2][2], cst[2][2];     // [row][colidx]
    float Wgx[DD_][2], Wox[DD_][2], bgv[2], bov[2];
    if (epi) {
#pragma unroll
        for (int ci = 0; ci < 2; ++ci) {
            const int c = ci ? c1 : c0;
            bgv[ci] = bg[c];
            bov[ci] = bo[c];
#pragma unroll
            for (int d = 0; d < DD_; ++d) {
                Wgx[d][ci] = Wg[d * H_ + c];
                Wox[d][ci] = Wo[d * H_ + c];
            }
#pragma unroll
            for (int r = 0; r < 2; ++r) {
                float ai = bi[c], af = bf_[c];
                for (int d = 0; d < DS_; ++d) {
                    float xv = xstat[(b0 + r) * DS_ + d];
                    ai += xv * Wi[d * H_ + c];
                    af += xv * Wf[d * H_ + c];
                }
                iG[r][ci]  = sigmoid_f(ai);
                fG[r][ci]  = sigmoid_f(af);
                cst[r][ci] = 0.0f;
            }
        }
    }

    half8_t Af[8];
    {
        half8_t z;
#pragma unroll
        for (int i = 0; i < 8; ++i) z[i] = (_Float16)0.0f;
#pragma unroll
        for (int ks = 0; ks < 8; ++ks) Af[ks] = z;
    }
    const bool areal = (lm < ROWS);

    __syncthreads();

    for (int t = 0; t < T_; ++t) {
        const int cur = t & 1;
        const int nxt = cur ^ 1;

        // A fragments for this step (issue loads first; lgkm waits hide under x-part)
        if (areal) {
#pragma unroll
            for (int ks = 0; ks < 8; ++ks)
                Af[ks] = *(const half8_t*)&hbuf[cur][lm][ks * 32 + 8 * lg];
        }

        // x-part pre-activations (independent of h -> overlaps ds_read / MFMA)
        float xgv[2][2], xov[2][2];
        if (epi) {
#pragma unroll
            for (int r = 0; r < 2; ++r) {
                float g0 = bgv[0], g1 = bgv[1], o0 = bov[0], o1 = bov[1];
#pragma unroll
                for (int d = 0; d < DD_; ++d) {
                    float xv = xsh[r][t * DD_ + d];
                    g0 += xv * Wgx[d][0];
                    g1 += xv * Wgx[d][1];
                    o0 += xv * Wox[d][0];
                    o1 += xv * Wox[d][1];
                }
                xgv[r][0] = g0; xgv[r][1] = g1;
                xov[r][0] = o0; xov[r][1] = o1;
            }
        }

        f32x4 accG0 = {0.f,0.f,0.f,0.f}, accG1 = {0.f,0.f,0.f,0.f};
        f32x4 accO0 = {0.f,0.f,0.f,0.f}, accO1 = {0.f,0.f,0.f,0.f};
#pragma unroll
        for (int ks = 0; ks < 8; ++ks) {
            accG0 = __builtin_amdgcn_mfma_f32_16x16x32_f16(Af[ks], Bf[0][0][ks], accG0, 0, 0, 0);
            accG1 = __builtin_amdgcn_mfma_f32_16x16x32_f16(Af[ks], Bf[0][1][ks], accG1, 0, 0, 0);
            accO0 = __builtin_amdgcn_mfma_f32_16x16x32_f16(Af[ks], Bf[1][0][ks], accO0, 0, 0, 0);
            accO1 = __builtin_amdgcn_mfma_f32_16x16x32_f16(Af[ks], Bf[1][1][ks], accO1, 0, 0, 0);
        }

        // in-register epilogue: lanes 0..15 hold rows 0,1 in acc regs 0,1
        if (epi) {
#pragma unroll
            for (int r = 0; r < 2; ++r) {
                float pg0 = accG0[r] + xgv[r][0];
                float pg1 = accG1[r] + xgv[r][1];
                float po0 = accO0[r] + xov[r][0];
                float po1 = accO1[r] + xov[r][1];
                float g0 = tanh_f(pg0), g1 = tanh_f(pg1);
                float o0 = sigmoid_f(po0), o1 = sigmoid_f(po1);
                cst[r][0] = fG[r][0] * cst[r][0] + iG[r][0] * g0;
                cst[r][1] = fG[r][1] * cst[r][1] + iG[r][1] * g1;
                float h0 = o0 * tanh_f(cst[r][0]);
                float h1 = o1 * tanh_f(cst[r][1]);
                hbuf[nxt][r][c0] = (_Float16)h0;
                hbuf[nxt][r][c1] = (_Float16)h1;
            }
        }
        __syncthreads();
    }

    // ---- output: out[b] = sum_c h[b][c] * Wh[c] + bh ----
    const int fin  = T_ & 1;           // buffer holding h(T)
    const int oc   = tid & 255;
    const int orow = tid >> 8;
    float v = (float)hbuf[fin][orow][oc] * Wh[oc];
#pragma unroll
    for (int off = 32; off > 0; off >>= 1)
        v += __shfl_down(v, off);
    if (l == 0) red[w] = v;
    __syncthreads();
    if (tid < ROWS) {
        out[b0 + tid] = red[tid * 4 + 0] + red[tid * 4 + 1]
                      + red[tid * 4 + 2] + red[tid * 4 + 3] + bh[0];
    }
}

extern "C" void kernel_launch(void* const* d_in, const int* in_sizes, int n_in,
                              void* d_out, int out_size, void* d_ws, size_t ws_size,
                              hipStream_t stream) {
    (void)in_sizes; (void)n_in; (void)out_size; (void)d_ws; (void)ws_size;
    const float* xdyn  = (const float*)d_in[0];
    const float* xstat = (const float*)d_in[1];
    const float* Wi    = (const float*)d_in[2];
    const float* bi    = (const float*)d_in[3];
    const float* Wf    = (const float*)d_in[4];
    const float* bf    = (const float*)d_in[5];
    const float* Wg    = (const float*)d_in[6];
    const float* bg    = (const float*)d_in[7];
    const float* Wo    = (const float*)d_in[8];
    const float* bo    = (const float*)d_in[9];
    const float* Wh    = (const float*)d_in[10];
    const float* bh    = (const float*)d_in[11];
    float* out = (float*)d_out;

    hipLaunchKernelGGL(ealstm_kernel, dim3(NBLK), dim3(NTHR), 0, stream,
                       xdyn, xstat, Wi, bi, Wf, bf, Wg, bg, Wo, bo, Wh, bh, out);
}

// Round 4
// 413.959 us; speedup vs baseline: 1.0675x; 1.0675x over previous
//
#include <hip/hip_runtime.h>

#define B_   512
#define T_   365
#define DD_  5
#define DS_  27
#define H_   256
#define ROWS 2
#define NBLK (B_ / ROWS)      // 256 blocks = 1 per CU
#define NW   8
#define NTHR (NW * 64)        // 512 threads

typedef _Float16 half8_t __attribute__((ext_vector_type(8)));
typedef float    f32x4   __attribute__((ext_vector_type(4)));

#define LOG2E_ 1.4426950408889634f

__device__ __forceinline__ float sigmoid_f(float x) {
    return __builtin_amdgcn_rcpf(1.0f + __builtin_amdgcn_exp2f(-x * LOG2E_));
}
__device__ __forceinline__ float tanh_f(float x) {
    return 1.0f - 2.0f * __builtin_amdgcn_rcpf(1.0f + __builtin_amdgcn_exp2f(2.0f * LOG2E_ * x));
}

__global__ __launch_bounds__(NTHR, 1)
void ealstm_kernel(const float* __restrict__ xdyn,   // [B,T,DD]
                   const float* __restrict__ xstat,  // [B,DS]
                   const float* __restrict__ Wi, const float* __restrict__ bi,
                   const float* __restrict__ Wf, const float* __restrict__ bf_,
                   const float* __restrict__ Wg, const float* __restrict__ bg,
                   const float* __restrict__ Wo, const float* __restrict__ bo,
                   const float* __restrict__ Wh, const float* __restrict__ bh,
                   float* __restrict__ out)
{
    const int tid = threadIdx.x;
    const int l   = tid & 63;
    const int w   = tid >> 6;
    const int b0  = blockIdx.x * ROWS;

    // h double-buffer: 16 rows (MFMA M) x 264 f16 (528B pitch)
    __shared__ __align__(16) _Float16 hbuf[2][16][264];
    __shared__ float xsh[ROWS][T_ * DD_];
    __shared__ float red[NW];

    // zero both h buffers (rows >= ROWS stay zero forever)
    {
        _Float16* hz = &hbuf[0][0][0];
        for (int i = tid; i < 2 * 16 * 264; i += NTHR) hz[i] = (_Float16)0.0f;
    }
    // preload x_dynamic for this block's rows
    for (int i = tid; i < ROWS * T_ * DD_; i += NTHR) {
        int r   = i / (T_ * DD_);
        int rem = i - r * (T_ * DD_);
        xsh[r][rem] = xdyn[(size_t)(b0 + r) * (T_ * DD_) + rem];
    }

    // ---- persistent B fragments (h-part weights, fp16, MFMA 16x16x32 layout)
    // wave w owns cols [w*32, w*32+32) as two 16x16 tiles, both matrices.
    // lane l holds B[k = ks*32 + 8*(l>>4) + i][col = tile_col + (l&15)]
    const int colW = w * 32;
    const int lg   = l >> 4;
    const int lm   = l & 15;
    half8_t Bf[2][2][8];
    {
#pragma unroll
        for (int m = 0; m < 2; ++m) {
            const float* Ws = (m == 0) ? Wg : Wo;
#pragma unroll
            for (int tt = 0; tt < 2; ++tt) {
#pragma unroll
                for (int ks = 0; ks < 8; ++ks) {
                    int col = colW + tt * 16 + lm;
                    int k   = ks * 32 + 8 * lg;
                    const float* p = Ws + (size_t)(DD_ + k) * H_ + col;
                    half8_t v;
#pragma unroll
                    for (int i = 0; i < 8; ++i) v[i] = (_Float16)p[(size_t)i * H_];
                    Bf[m][tt][ks] = v;
                }
            }
        }
    }

    // ---- per-lane epilogue state: cols c0 (tile0), c1 (tile1); rows 0..1.
    // Lanes 16..63 duplicate lanes 0..15's state (same l&15) — computed
    // uniformly to avoid divergence; only stores are masked.
    const int c0 = colW + lm;
    const int c1 = c0 + 16;

    float iG[2][2], fG[2][2], cst[2][2];     // [row][colidx]
    float Wgx[DD_][2], Wox[DD_][2], bgv[2], bov[2];
#pragma unroll
    for (int ci = 0; ci < 2; ++ci) {
        const int c = ci ? c1 : c0;
        bgv[ci] = bg[c];
        bov[ci] = bo[c];
#pragma unroll
        for (int d = 0; d < DD_; ++d) {
            Wgx[d][ci] = Wg[d * H_ + c];
            Wox[d][ci] = Wo[d * H_ + c];
        }
#pragma unroll
        for (int r = 0; r < 2; ++r) {
            float ai = bi[c], af = bf_[c];
            for (int d = 0; d < DS_; ++d) {
                float xv = xstat[(b0 + r) * DS_ + d];
                ai += xv * Wi[d * H_ + c];
                af += xv * Wf[d * H_ + c];
            }
            iG[r][ci]  = sigmoid_f(ai);
            fG[r][ci]  = sigmoid_f(af);
            cst[r][ci] = 0.0f;
        }
    }

    half8_t Af[8];
    {
        half8_t z;
#pragma unroll
        for (int i = 0; i < 8; ++i) z[i] = (_Float16)0.0f;
#pragma unroll
        for (int ks = 0; ks < 8; ++ks) Af[ks] = z;
    }
    const bool areal = (lm < ROWS);   // 8 lanes/wave load real h rows; rest keep zeros
    const bool epi   = (l < 16);      // store mask only

    __syncthreads();

    for (int t = 0; t < T_; ++t) {
        const int cur = t & 1;
        const int nxt = cur ^ 1;

        // A fragments for this step
        if (areal) {
#pragma unroll
            for (int ks = 0; ks < 8; ++ks)
                Af[ks] = *(const half8_t*)&hbuf[cur][lm][ks * 32 + 8 * lg];
        }

        // x-part pre-activations -> accumulator C-init (rows 0,1 = regs 0,1 on
        // lanes 0..15; every other (lane,reg) slot is a garbage row, value moot)
        float xg0 = bgv[0], xg1 = bgv[1], xo0 = bov[0], xo1 = bov[1];
        float yg0 = bgv[0], yg1 = bgv[1], yo0 = bov[0], yo1 = bov[1];
#pragma unroll
        for (int d = 0; d < DD_; ++d) {
            float x0 = xsh[0][t * DD_ + d];
            float x1 = xsh[1][t * DD_ + d];
            xg0 += x0 * Wgx[d][0];  xg1 += x0 * Wgx[d][1];
            xo0 += x0 * Wox[d][0];  xo1 += x0 * Wox[d][1];
            yg0 += x1 * Wgx[d][0];  yg1 += x1 * Wgx[d][1];
            yo0 += x1 * Wox[d][0];  yo1 += x1 * Wox[d][1];
        }

        f32x4 accG0 = {xg0, yg0, 0.f, 0.f};
        f32x4 accG1 = {xg1, yg1, 0.f, 0.f};
        f32x4 accO0 = {xo0, yo0, 0.f, 0.f};
        f32x4 accO1 = {xo1, yo1, 0.f, 0.f};
#pragma unroll
        for (int ks = 0; ks < 8; ++ks) {
            accG0 = __builtin_amdgcn_mfma_f32_16x16x32_f16(Af[ks], Bf[0][0][ks], accG0, 0, 0, 0);
            accG1 = __builtin_amdgcn_mfma_f32_16x16x32_f16(Af[ks], Bf[0][1][ks], accG1, 0, 0, 0);
            accO0 = __builtin_amdgcn_mfma_f32_16x16x32_f16(Af[ks], Bf[1][0][ks], accO0, 0, 0, 0);
            accO1 = __builtin_amdgcn_mfma_f32_16x16x32_f16(Af[ks], Bf[1][1][ks], accO1, 0, 0, 0);
        }

        // in-register epilogue (uniform math; garbage lanes compute garbage)
#pragma unroll
        for (int r = 0; r < 2; ++r) {
            float g0 = tanh_f(r ? accG0[1] : accG0[0]);
            float g1 = tanh_f(r ? accG1[1] : accG1[0]);
            float o0 = sigmoid_f(r ? accO0[1] : accO0[0]);
            float o1 = sigmoid_f(r ? accO1[1] : accO1[0]);
            cst[r][0] = fG[r][0] * cst[r][0] + iG[r][0] * g0;
            cst[r][1] = fG[r][1] * cst[r][1] + iG[r][1] * g1;
            float h0 = o0 * tanh_f(cst[r][0]);
            float h1 = o1 * tanh_f(cst[r][1]);
            if (epi) {
                hbuf[nxt][r][c0] = (_Float16)h0;
                hbuf[nxt][r][c1] = (_Float16)h1;
            }
        }
        __syncthreads();
    }

    // ---- output: out[b] = sum_c h[b][c] * Wh[c] + bh ----
    const int fin  = T_ & 1;           // buffer holding h(T)
    const int oc   = tid & 255;
    const int orow = tid >> 8;
    float v = (float)hbuf[fin][orow][oc] * Wh[oc];
#pragma unroll
    for (int off = 32; off > 0; off >>= 1)
        v += __shfl_down(v, off);
    if (l == 0) red[w] = v;
    __syncthreads();
    if (tid < ROWS) {
        out[b0 + tid] = red[tid * 4 + 0] + red[tid * 4 + 1]
                      + red[tid * 4 + 2] + red[tid * 4 + 3] + bh[0];
    }
}

extern "C" void kernel_launch(void* const* d_in, const int* in_sizes, int n_in,
                              void* d_out, int out_size, void* d_ws, size_t ws_size,
                              hipStream_t stream) {
    (void)in_sizes; (void)n_in; (void)out_size; (void)d_ws; (void)ws_size;
    const float* xdyn  = (const float*)d_in[0];
    const float* xstat = (const float*)d_in[1];
    const float* Wi    = (const float*)d_in[2];
    const float* bi    = (const float*)d_in[3];
    const float* Wf    = (const float*)d_in[4];
    const float* bf    = (const float*)d_in[5];
    const float* Wg    = (const float*)d_in[6];
    const float* bg    = (const float*)d_in[7];
    const float* Wo    = (const float*)d_in[8];
    const float* bo    = (const float*)d_in[9];
    const float* Wh    = (const float*)d_in[10];
    const float* bh    = (const float*)d_in[11];
    float* out = (float*)d_out;

    hipLaunchKernelGGL(ealstm_kernel, dim3(NBLK), dim3(NTHR), 0, stream,
                       xdyn, xstat, Wi, bi, Wf, bf, Wg, bg, Wo, bo, Wh, bh, out);
}

// Round 5
// 310.232 us; speedup vs baseline: 1.4244x; 1.3344x over previous
//
#include <hip/hip_runtime.h>

#define B_   512
#define T_   365
#define DD_  5
#define DS_  27
#define H_   256
#define ROWS 2
#define NBLK (B_ / ROWS)      // 256 blocks = 1 per CU
#define NW   8
#define NTHR (NW * 64)        // 512 threads

typedef _Float16 half8_t __attribute__((ext_vector_type(8)));
typedef float    f32x4   __attribute__((ext_vector_type(4)));

#define LOG2E_ 1.4426950408889634f

__device__ __forceinline__ float sigmoid_f(float x) {
    return __builtin_amdgcn_rcpf(1.0f + __builtin_amdgcn_exp2f(-x * LOG2E_));
}
__device__ __forceinline__ float tanh_f(float x) {
    return 1.0f - 2.0f * __builtin_amdgcn_rcpf(1.0f + __builtin_amdgcn_exp2f(2.0f * LOG2E_ * x));
}

__global__ __launch_bounds__(NTHR, 2)
void ealstm_kernel(const float* __restrict__ xdyn,   // [B,T,DD]
                   const float* __restrict__ xstat,  // [B,DS]
                   const float* __restrict__ Wi, const float* __restrict__ bi,
                   const float* __restrict__ Wf, const float* __restrict__ bf_,
                   const float* __restrict__ Wg, const float* __restrict__ bg,
                   const float* __restrict__ Wo, const float* __restrict__ bo,
                   const float* __restrict__ Wh, const float* __restrict__ bh,
                   float* __restrict__ out)
{
    const int tid = threadIdx.x;
    const int l   = tid & 63;
    const int w   = tid >> 6;
    const int b0  = blockIdx.x * ROWS;

    // h double-buffer: 16 rows (MFMA M) x 264 f16 (528B pitch)
    __shared__ __align__(16) _Float16 hbuf[2][16][264];
    __shared__ float xsh[ROWS][T_ * DD_];
    __shared__ float red[NW];

    // zero both h buffers (rows >= ROWS stay zero forever)
    {
        _Float16* hz = &hbuf[0][0][0];
        for (int i = tid; i < 2 * 16 * 264; i += NTHR) hz[i] = (_Float16)0.0f;
    }
    // preload x_dynamic for this block's rows
    for (int i = tid; i < ROWS * T_ * DD_; i += NTHR) {
        int r   = i / (T_ * DD_);
        int rem = i - r * (T_ * DD_);
        xsh[r][rem] = xdyn[(size_t)(b0 + r) * (T_ * DD_) + rem];
    }

    // ---- persistent B fragments (h-part weights, fp16, MFMA 16x16x32 layout)
    // wave w owns cols [w*32, w*32+32) as two 16x16 tiles, both matrices.
    // lane l holds B[k = ks*32 + 8*(l>>4) + i][col = tile_col + (l&15)]
    const int colW = w * 32;
    const int lg   = l >> 4;
    const int lm   = l & 15;
    half8_t Bf[2][2][8];
    {
#pragma unroll
        for (int m = 0; m < 2; ++m) {
            const float* Ws = (m == 0) ? Wg : Wo;
#pragma unroll
            for (int tt = 0; tt < 2; ++tt) {
#pragma unroll
                for (int ks = 0; ks < 8; ++ks) {
                    int col = colW + tt * 16 + lm;
                    int k   = ks * 32 + 8 * lg;
                    const float* p = Ws + (size_t)(DD_ + k) * H_ + col;
                    half8_t v;
#pragma unroll
                    for (int i = 0; i < 8; ++i) v[i] = (_Float16)p[(size_t)i * H_];
                    Bf[m][tt][ks] = v;
                }
            }
        }
    }

    // ---- per-lane epilogue ownership: ONE (row, col) element per lane ----
    // lane l: row r_l = (l>>4)&1 ; col c_l = colW + (l>>5)*16 + (l&15)
    const int r_l = (l >> 4) & 1;
    const int ch  = l >> 5;              // which 16-col tile
    const int c_l = colW + ch * 16 + lm;
    const int s_l = lm;                  // shfl source lane (acc rows live on lanes 0..15)

    float Wgx[DD_], Wox[DD_];
#pragma unroll
    for (int d = 0; d < DD_; ++d) {
        Wgx[d] = Wg[d * H_ + c_l];
        Wox[d] = Wo[d * H_ + c_l];
    }
    const float bgv = bg[c_l], bov = bo[c_l];

    float iG, fG, cst = 0.0f;
    {
        float ai = bi[c_l], af = bf_[c_l];
        for (int d = 0; d < DS_; ++d) {
            float xv = xstat[(b0 + r_l) * DS_ + d];
            ai += xv * Wi[d * H_ + c_l];
            af += xv * Wf[d * H_ + c_l];
        }
        iG = sigmoid_f(ai);
        fG = sigmoid_f(af);
    }

    half8_t Af[8];
    {
        half8_t z;
#pragma unroll
        for (int i = 0; i < 8; ++i) z[i] = (_Float16)0.0f;
#pragma unroll
        for (int ks = 0; ks < 8; ++ks) Af[ks] = z;
    }
    const bool areal = (lm < ROWS);   // 2 lanes per 16-group load real h rows

    __syncthreads();

    for (int t = 0; t < T_; ++t) {
        const int cur = t & 1;
        const int nxt = cur ^ 1;

        // A fragments for this step (hbuf[cur] valid after prev barrier)
        if (areal) {
#pragma unroll
            for (int ks = 0; ks < 8; ++ks)
                Af[ks] = *(const half8_t*)&hbuf[cur][lm][ks * 32 + 8 * lg];
        }

        // per-lane x-part (h-independent -> overlaps Af lgkm wait)
        float xg = bgv, xo = bov;
#pragma unroll
        for (int d = 0; d < DD_; ++d) {
            float xv = xsh[r_l][t * DD_ + d];
            xg += xv * Wgx[d];
            xo += xv * Wox[d];
        }

        f32x4 accG0 = {0.f,0.f,0.f,0.f}, accG1 = {0.f,0.f,0.f,0.f};
        f32x4 accO0 = {0.f,0.f,0.f,0.f}, accO1 = {0.f,0.f,0.f,0.f};
#pragma unroll
        for (int ks = 0; ks < 8; ++ks) {
            accG0 = __builtin_amdgcn_mfma_f32_16x16x32_f16(Af[ks], Bf[0][0][ks], accG0, 0, 0, 0);
            accG1 = __builtin_amdgcn_mfma_f32_16x16x32_f16(Af[ks], Bf[0][1][ks], accG1, 0, 0, 0);
            accO0 = __builtin_amdgcn_mfma_f32_16x16x32_f16(Af[ks], Bf[1][0][ks], accO0, 0, 0, 0);
            accO1 = __builtin_amdgcn_mfma_f32_16x16x32_f16(Af[ks], Bf[1][1][ks], accO1, 0, 0, 0);
        }

        // redistribute: lane l pulls its (r_l, c_l) pre-activation from lane s_l
        float g00 = __shfl(accG0[0], s_l), g01 = __shfl(accG0[1], s_l);
        float g10 = __shfl(accG1[0], s_l), g11 = __shfl(accG1[1], s_l);
        float o00 = __shfl(accO0[0], s_l), o01 = __shfl(accO0[1], s_l);
        float o10 = __shfl(accO1[0], s_l), o11 = __shfl(accO1[1], s_l);
        float pg = ch ? (r_l ? g11 : g10) : (r_l ? g01 : g00);
        float po = ch ? (r_l ? o11 : o10) : (r_l ? o01 : o00);
        pg += xg;
        po += xo;

        float g = tanh_f(pg);
        float o = sigmoid_f(po);
        cst = fG * cst + iG * g;
        float hv = o * tanh_f(cst);
        hbuf[nxt][r_l][c_l] = (_Float16)hv;

        __syncthreads();
    }

    // ---- output: out[b] = sum_c h[b][c] * Wh[c] + bh ----
    const int fin  = T_ & 1;           // buffer holding h(T)
    const int oc   = tid & 255;
    const int orow = tid >> 8;
    float v = (float)hbuf[fin][orow][oc] * Wh[oc];
#pragma unroll
    for (int off = 32; off > 0; off >>= 1)
        v += __shfl_down(v, off);
    if (l == 0) red[w] = v;
    __syncthreads();
    if (tid < ROWS) {
        out[b0 + tid] = red[tid * 4 + 0] + red[tid * 4 + 1]
                      + red[tid * 4 + 2] + red[tid * 4 + 3] + bh[0];
    }
}

extern "C" void kernel_launch(void* const* d_in, const int* in_sizes, int n_in,
                              void* d_out, int out_size, void* d_ws, size_t ws_size,
                              hipStream_t stream) {
    (void)in_sizes; (void)n_in; (void)out_size; (void)d_ws; (void)ws_size;
    const float* xdyn  = (const float*)d_in[0];
    const float* xstat = (const float*)d_in[1];
    const float* Wi    = (const float*)d_in[2];
    const float* bi    = (const float*)d_in[3];
    const float* Wf    = (const float*)d_in[4];
    const float* bf    = (const float*)d_in[5];
    const float* Wg    = (const float*)d_in[6];
    const float* bg    = (const float*)d_in[7];
    const float* Wo    = (const float*)d_in[8];
    const float* bo    = (const float*)d_in[9];
    const float* Wh    = (const float*)d_in[10];
    const float* bh    = (const float*)d_in[11];
    float* out = (float*)d_out;

    hipLaunchKernelGGL(ealstm_kernel, dim3(NBLK), dim3(NTHR), 0, stream,
                       xdyn, xstat, Wi, bi, Wf, bf, Wg, bg, Wo, bo, Wh, bh, out);
}